// Round 19
// baseline (68.540 us; speedup 1.0000x reference)
//
#include <hip/hip_runtime.h>

typedef __attribute__((ext_vector_type(4)))  float f32x4;
typedef __attribute__((ext_vector_type(16))) float f32x16;
typedef __attribute__((ext_vector_type(8)))  short short8;

#define DEVI static __device__ __forceinline__

constexpr int B_ = 4;
constexpr int N_ = 4096;
constexpr int H_ = 128;
constexpr size_t ELEMS = (size_t)B_ * N_ * H_;   // per tensor
constexpr size_t TSB = ELEMS * 2;                // bf16 bytes per tensor

// ---- v19 geometry: R18 kernel, 3 waves/SIMD (slim regset), KS=8 ----
constexpr int QT = 128;
constexpr int KVB = 32;
constexpr int NTH = 256;
constexpr int KS8 = 8;

DEVI unsigned short f2bf(float x) {
  union { float f; unsigned u; } a; a.f = x;
  unsigned u = a.u;
  return (unsigned short)((u + 0x7FFFu + ((u >> 16) & 1u)) >> 16);  // RNE
}

DEVI unsigned cvt_pk_bf16(float lo, float hi) {
  unsigned w;
  asm("v_cvt_pk_bf16_f32 %0, %1, %2" : "=v"(w) : "v"(lo), "v"(hi));
  return w;
}

DEVI float bf2f(unsigned short u) {
  union { unsigned u; float f; } a; a.u = (unsigned)u << 16;
  return a.f;
}

DEVI void gl_lds16(const void* g, void* l) {
  __builtin_amdgcn_global_load_lds(
      (const __attribute__((address_space(1))) void*)g,
      (__attribute__((address_space(3))) void*)l, 16, 0, 0);
}

// ---------------- merged pre-pass: Q(scaled)/K bf16 + V^T bf16 ----------------
__global__ void conv_all(const float* __restrict__ q, const float* __restrict__ k,
                         const float* __restrict__ v,
                         unsigned short* __restrict__ qb, unsigned short* __restrict__ kb,
                         unsigned short* __restrict__ vt) {
  __shared__ unsigned short T[64][72];
  const int bid = blockIdx.x;
  const int t = threadIdx.x;
  if (bid < 1024) {
    const float qscale = 0.08838834764831845f * 1.4426950408889634f;  // 1/sqrt(H)*log2e
    size_t i = (size_t)bid * 256 + t;  // vec8 index
    {
      const float4* s = (const float4*)q + 2 * i;
      float4 a = s[0], b = s[1];
      short8 o;
      o[0] = (short)f2bf(a.x * qscale); o[1] = (short)f2bf(a.y * qscale);
      o[2] = (short)f2bf(a.z * qscale); o[3] = (short)f2bf(a.w * qscale);
      o[4] = (short)f2bf(b.x * qscale); o[5] = (short)f2bf(b.y * qscale);
      o[6] = (short)f2bf(b.z * qscale); o[7] = (short)f2bf(b.w * qscale);
      *(short8*)(qb + i * 8) = o;
    }
    {
      const float4* s = (const float4*)k + 2 * i;
      float4 a = s[0], b = s[1];
      short8 o;
      o[0] = (short)f2bf(a.x); o[1] = (short)f2bf(a.y);
      o[2] = (short)f2bf(a.z); o[3] = (short)f2bf(a.w);
      o[4] = (short)f2bf(b.x); o[5] = (short)f2bf(b.y);
      o[6] = (short)f2bf(b.z); o[7] = (short)f2bf(b.w);
      *(short8*)(kb + i * 8) = o;
    }
  } else {
    const int vb = bid - 1024;          // 512 tiles: [64 n][64 h]
    const int n0 = (vb & 63) * 64, h0 = ((vb >> 6) & 1) * 64, b = vb >> 7;
    const int c4 = t & 15, r = t >> 4;
#pragma unroll
    for (int i = 0; i < 4; ++i) {
      int n = n0 + r + 16 * i;
      float4 val = *(const float4*)(v + ((size_t)b * N_ + n) * H_ + h0 + 4 * c4);
      T[4 * c4 + 0][r + 16 * i] = f2bf(val.x);
      T[4 * c4 + 1][r + 16 * i] = f2bf(val.y);
      T[4 * c4 + 2][r + 16 * i] = f2bf(val.z);
      T[4 * c4 + 3][r + 16 * i] = f2bf(val.w);
    }
    __syncthreads();
    const int c8 = t & 7, hr = t >> 3;
#pragma unroll
    for (int i = 0; i < 2; ++i) {
      int hl = hr + 32 * i;
      short8 val = *(const short8*)(&T[hl][8 * c8]);
      *(short8*)(vt + ((size_t)b * H_ + h0 + hl) * N_ + n0 + 8 * c8) = val;
    }
  }
}

// ------- main v19: R18 body at 3 waves/SIMD, KS=8 (1024 blocks, 3-4/CU) -------
__global__ __launch_bounds__(NTH, 3)
void fattn_v19(const unsigned short* __restrict__ qws,
               const unsigned short* __restrict__ kws,
               const unsigned short* __restrict__ vtws,
               unsigned short* __restrict__ opart, float* __restrict__ mlpart) {
  constexpr int KS = KS8;
  constexpr int KVRANGE = N_ / KS;     // 512
  constexpr int NST = KVRANGE / KVB;   // 16

  __shared__ __align__(16) char smem[36864];
  char* Kb0 = smem;              // 2 x 8192: K [32 kv][256B], swz (row&15)<<4
  char* Vb0 = smem + 16384;      // 2 x 10240: V^T padded [128 h][80B]

  const int tid = threadIdx.x, wave = tid >> 6, lane = tid & 63;
  const int l31 = lane & 31, half = lane >> 5;

  // 1024 blocks: xcd = bid&7 owns 4 (b,z) pairs -> K/V slices L2-resident
  const int bid = blockIdx.x;
  const int pair = (bid & 7) * 4 + ((bid >> 3) & 3);
  const int x = bid >> 5;              // q-tile 0..31
  const int b = pair / KS, z = pair % KS;

  const int qg0 = x * QT + wave * 32;
  const size_t kvz = (size_t)z * KVRANGE;

  const unsigned short* qp0 = qws + ((size_t)b * N_ + qg0 + l31) * H_ + 8 * half;
  short8 qf[8];
#pragma unroll
  for (int c = 0; c < 8; ++c) qf[c] = *(const short8*)(qp0 + 16 * c);

  f32x16 O0 = {}, O1 = {}, O2 = {}, O3 = {};
  float m = 0.f, l = 0.f;        // m wave-uniform; l LANE-LOCAL (half-row sum)

  const char* kbase = (const char*)(kws + ((size_t)b * N_ + kvz) * H_);
  const char* vbase = (const char*)(vtws + (size_t)b * H_ * N_) + kvz * 2;

  const int vh = tid >> 1;             // V staging: h row (2 thr/row)
  const int vc = (tid & 1) * 2;        // chunk base {0,2} x16B

  // ---- prologue: stage K(0) ----
#pragma unroll
  for (int i = 0; i < 2; ++i) {
    int off = (tid + 256 * i) * 16;
    int row = off >> 8, col = off & 255;
    gl_lds16(kbase + row * 256 + (col ^ ((row & 15) << 4)), Kb0 + off);
  }
  __syncthreads();

  const int kswz = (l31 & 15) << 4;
  const int kcol = 16 * half;
  short8 pfa = {}, pfb = {};           // P frags carried across iterations

  for (int st = 0; st < NST; ++st) {
    // ---- issue staging: K(st+1) via gl_lds, V(st) into regs ----
    if (st + 1 < NST) {
      const char* kt = kbase + (size_t)(st + 1) * KVB * H_ * 2;
      char* kd = Kb0 + ((st + 1) & 1) * 8192;
#pragma unroll
      for (int i = 0; i < 2; ++i) {
        int off = (tid + 256 * i) * 16;
        int row = off >> 8, col = off & 255;
        gl_lds16(kt + row * 256 + (col ^ ((row & 15) << 4)), kd + off);
      }
    }
    const char* vsrc = vbase + (size_t)st * KVB * 2 + (size_t)vh * (N_ * 2) + vc * 16;
    uint4 vr0 = *(const uint4*)(vsrc);
    uint4 vr1 = *(const uint4*)(vsrc + 16);

    // ---- MFMA cluster: PV(st-1) + QKT(st) ----
    __builtin_amdgcn_s_setprio(1);
    if (st > 0) {
      const char* Vl = Vb0 + ((st - 1) & 1) * 10240;
      const char* vrow = Vl + l31 * 80 + 16 * half;
      short8 a00 = *(const short8*)(vrow + 0 * 2560);
      short8 a10 = *(const short8*)(vrow + 1 * 2560);
      short8 a20 = *(const short8*)(vrow + 2 * 2560);
      short8 a30 = *(const short8*)(vrow + 3 * 2560);
      O0 = __builtin_amdgcn_mfma_f32_32x32x16_bf16(a00, pfa, O0, 0, 0, 0);
      O1 = __builtin_amdgcn_mfma_f32_32x32x16_bf16(a10, pfa, O1, 0, 0, 0);
      O2 = __builtin_amdgcn_mfma_f32_32x32x16_bf16(a20, pfa, O2, 0, 0, 0);
      O3 = __builtin_amdgcn_mfma_f32_32x32x16_bf16(a30, pfa, O3, 0, 0, 0);
      short8 a01 = *(const short8*)(vrow + 32 + 0 * 2560);
      short8 a11 = *(const short8*)(vrow + 32 + 1 * 2560);
      short8 a21 = *(const short8*)(vrow + 32 + 2 * 2560);
      short8 a31 = *(const short8*)(vrow + 32 + 3 * 2560);
      O0 = __builtin_amdgcn_mfma_f32_32x32x16_bf16(a01, pfb, O0, 0, 0, 0);
      O1 = __builtin_amdgcn_mfma_f32_32x32x16_bf16(a11, pfb, O1, 0, 0, 0);
      O2 = __builtin_amdgcn_mfma_f32_32x32x16_bf16(a21, pfb, O2, 0, 0, 0);
      O3 = __builtin_amdgcn_mfma_f32_32x32x16_bf16(a31, pfb, O3, 0, 0, 0);
    }
    {
      const char* Kl = Kb0 + (st & 1) * 8192;
      f32x16 S = {};
#pragma unroll
      for (int c = 0; c < 8; ++c) {
        short8 af = *(const short8*)(Kl + l31 * 256 + ((32 * c + kcol) ^ kswz));
        S = __builtin_amdgcn_mfma_f32_32x32x16_bf16(af, qf[c], S, 0, 0, 0);
      }
      __builtin_amdgcn_s_setprio(0);

      // ---- SM(st): p = exp2(S - m); speculative pack, lane-local rs/l ----
      float p[16];
#pragma unroll
      for (int i = 0; i < 16; ++i) p[i] = __builtin_amdgcn_exp2f(S[i] - m);
      unsigned u0 = cvt_pk_bf16(p[0], p[1]),   u1 = cvt_pk_bf16(p[2], p[3]);
      unsigned u2 = cvt_pk_bf16(p[4], p[5]),   u3 = cvt_pk_bf16(p[6], p[7]);
      unsigned u4 = cvt_pk_bf16(p[8], p[9]),   u5 = cvt_pk_bf16(p[10], p[11]);
      unsigned u6 = cvt_pk_bf16(p[12], p[13]), u7 = cvt_pk_bf16(p[14], p[15]);
      unsigned ra = __shfl_xor((int)(half ? u0 : u2), 32);
      unsigned rb = __shfl_xor((int)(half ? u1 : u3), 32);
      unsigned rc = __shfl_xor((int)(half ? u4 : u6), 32);
      unsigned rd = __shfl_xor((int)(half ? u5 : u7), 32);
      union { unsigned u[4]; short8 s; } f0, f1;
      f0.u[0] = half ? ra : u0;  f0.u[1] = half ? rb : u1;
      f0.u[2] = half ? u2 : ra;  f0.u[3] = half ? u3 : rb;
      f1.u[0] = half ? rc : u4;  f1.u[1] = half ? rd : u5;
      f1.u[2] = half ? u6 : rc;  f1.u[3] = half ? u7 : rd;
      pfa = f0.s;
      pfb = f1.s;

      float rs = (((p[0] + p[1]) + (p[2] + p[3])) + ((p[4] + p[5]) + (p[6] + p[7]))) +
                 (((p[8] + p[9]) + (p[10] + p[11])) + ((p[12] + p[13]) + (p[14] + p[15])));
      l += rs;   // lane-local half-row sum; reduced once in epilogue
      if (__builtin_expect(!__all(rs <= 524288.f), 0)) {
        // cold path: full rescale + repack
        float rsw = rs + __shfl_xor(rs, 32);
        float ai = 1.f / rsw;
        m += __builtin_amdgcn_logf(rsw);       // v_log_f32 = log2
        l *= ai;
#pragma unroll
        for (int i = 0; i < 16; ++i) p[i] *= ai;
#pragma unroll
        for (int i = 0; i < 16; ++i) { O0[i] *= ai; O1[i] *= ai; O2[i] *= ai; O3[i] *= ai; }
        unsigned v0 = cvt_pk_bf16(p[0], p[1]),   v1 = cvt_pk_bf16(p[2], p[3]);
        unsigned v2 = cvt_pk_bf16(p[4], p[5]),   v3 = cvt_pk_bf16(p[6], p[7]);
        unsigned v4 = cvt_pk_bf16(p[8], p[9]),   v5 = cvt_pk_bf16(p[10], p[11]);
        unsigned v6 = cvt_pk_bf16(p[12], p[13]), v7 = cvt_pk_bf16(p[14], p[15]);
        unsigned sa = __shfl_xor((int)(half ? v0 : v2), 32);
        unsigned sb = __shfl_xor((int)(half ? v1 : v3), 32);
        unsigned sc2 = __shfl_xor((int)(half ? v4 : v6), 32);
        unsigned sd = __shfl_xor((int)(half ? v5 : v7), 32);
        union { unsigned u[4]; short8 s; } g0, g1;
        g0.u[0] = half ? sa : v0;  g0.u[1] = half ? sb : v1;
        g0.u[2] = half ? v2 : sa;  g0.u[3] = half ? v3 : sb;
        g1.u[0] = half ? sc2 : v4; g1.u[1] = half ? sd : v5;
        g1.u[2] = half ? v6 : sc2; g1.u[3] = half ? v7 : sd;
        pfa = g0.s;
        pfb = g1.s;
      }
    }

    // ---- late write of V(st) regs (vmcnt wait covers K(st+1) gl_lds too) ----
    {
      char* vd = Vb0 + (st & 1) * 10240 + vh * 80 + vc * 16;
      *(uint4*)(vd) = vr0;
      *(uint4*)(vd + 16) = vr1;
    }
    __syncthreads();
  }

  // ---- epilogue: final PV(NST-1) ----
  {
    const char* Vl = Vb0 + ((NST - 1) & 1) * 10240;
    const char* vrow = Vl + l31 * 80 + 16 * half;
#pragma unroll
    for (int t2 = 0; t2 < 4; ++t2) {
      short8 a0 = *(const short8*)(vrow + t2 * 2560);
      short8 a1 = *(const short8*)(vrow + 32 + t2 * 2560);
      f32x16 acc = (t2 == 0) ? O0 : (t2 == 1) ? O1 : (t2 == 2) ? O2 : O3;
      acc = __builtin_amdgcn_mfma_f32_32x32x16_bf16(a0, pfa, acc, 0, 0, 0);
      acc = __builtin_amdgcn_mfma_f32_32x32x16_bf16(a1, pfb, acc, 0, 0, 0);
      if (t2 == 0) O0 = acc; else if (t2 == 1) O1 = acc; else if (t2 == 2) O2 = acc; else O3 = acc;
    }
  }

  // ---- l: reduce lane-local halves once ----
  float lw = l + __shfl_xor(l, 32);

  // ---- stores (bf16 partials): lane q = l31, h = 32*t2 + 8g + 4*half + j ----
  const size_t zb = (size_t)z * B_ + b;
  if (half == 0) {
    float2 ml = {m, lw};
    *(float2*)(mlpart + 2 * (zb * N_ + qg0 + l31)) = ml;
  }
  unsigned short* od = opart + (zb * N_ + qg0 + l31) * H_ + 4 * half;
#pragma unroll
  for (int g = 0; g < 4; ++g) {
    uint2 w0 = {cvt_pk_bf16(O0[4 * g], O0[4 * g + 1]), cvt_pk_bf16(O0[4 * g + 2], O0[4 * g + 3])};
    uint2 w1 = {cvt_pk_bf16(O1[4 * g], O1[4 * g + 1]), cvt_pk_bf16(O1[4 * g + 2], O1[4 * g + 3])};
    uint2 w2 = {cvt_pk_bf16(O2[4 * g], O2[4 * g + 1]), cvt_pk_bf16(O2[4 * g + 2], O2[4 * g + 3])};
    uint2 w3 = {cvt_pk_bf16(O3[4 * g], O3[4 * g + 1]), cvt_pk_bf16(O3[4 * g + 2], O3[4 * g + 3])};
    *(uint2*)(od + 8 * g) = w0;
    *(uint2*)(od + 32 + 8 * g) = w1;
    *(uint2*)(od + 64 + 8 * g) = w2;
    *(uint2*)(od + 96 + 8 * g) = w3;
  }
}

// ---------------- combine the KS kv-split partials (bf16 opart) ----------------
template <int KS>
__global__ void combine_k(const unsigned short* __restrict__ opart,
                          const float* __restrict__ mlpart,
                          float* __restrict__ out) {
  const int t = threadIdx.x;
  size_t row = (size_t)blockIdx.x * 8 + (t >> 5);
  int hc = (t & 31) * 4;
  float mz[KS], lz[KS];
  float mi = -__builtin_inff();
#pragma unroll
  for (int z = 0; z < KS; ++z) {
    size_t r = (size_t)z * B_ * N_ + row;
    mz[z] = mlpart[2 * r];
    lz[z] = mlpart[2 * r + 1];
    mi = fmaxf(mi, mz[z]);
  }
  float lsum = 0.f;
  float az[KS];
#pragma unroll
  for (int z = 0; z < KS; ++z) {
    az[z] = __builtin_amdgcn_exp2f(mz[z] - mi);
    lsum += az[z] * lz[z];
  }
  float rinv = 1.f / lsum;
  f32x4 acc = {};
#pragma unroll
  for (int z = 0; z < KS; ++z) {
    const unsigned short* op = opart + (size_t)z * B_ * N_ * H_ + row * H_ + hc;
    ushort4 u = *(const ushort4*)(op);
    f32x4 oz = {bf2f(u.x), bf2f(u.y), bf2f(u.z), bf2f(u.w)};
    acc = acc + oz * (az[z] * rinv);
  }
  *(f32x4*)(out + row * H_ + hc) = acc;
}

// ================= fallback path (minimal ws): R2-proven pipeline =================
constexpr int FB_QTILE = 64;
constexpr int FB_KVSTEP = 128;
constexpr int FB_KVHALF = 64;
constexpr int FB_NTH = 512;
constexpr int FB_NSTEPS = N_ / FB_KVSTEP;

__global__ __launch_bounds__(FB_NTH, 2)
void fattn_fast(const unsigned short* __restrict__ qws,
                const unsigned short* __restrict__ kws,
                const unsigned short* __restrict__ vtws,
                float* __restrict__ out) {
  __shared__ unsigned short Kbuf[2][FB_KVSTEP * H_];
  __shared__ unsigned short Vbuf[2][H_ * FB_KVSTEP];
  __shared__ unsigned short Plds[8][16 * FB_KVHALF];
  __shared__ float MLlds[4][16][2];

  const int tid = threadIdx.x;
  const int wave = tid >> 6;
  const int lane = tid & 63;
  const int l15 = lane & 15;
  const int l4 = lane >> 4;
  const int sub = wave & 3;
  const int grp = wave >> 2;

  const int b = blockIdx.y;
  const int qbase = blockIdx.x * FB_QTILE;

  const unsigned short* qp = qws + ((size_t)b * N_ + qbase + sub * 16 + l15) * H_;
  short8 qfrag[4];
#pragma unroll
  for (int kc = 0; kc < 4; ++kc)
    qfrag[kc] = *(const short8*)(qp + 8 * l4 + 32 * kc);

  f32x4 Oacc[8];
#pragma unroll
  for (int i = 0; i < 8; ++i) Oacc[i] = (f32x4){0.f, 0.f, 0.f, 0.f};
  float mrun[4], lrun[4];
#pragma unroll
  for (int r = 0; r < 4; ++r) { mrun[r] = -__builtin_inff(); lrun[r] = 0.f; }

  const char* kbase = (const char*)(kws + (size_t)b * N_ * H_);
  const char* vbase = (const char*)(vtws + (size_t)b * H_ * N_);
  const int kvbase = grp * FB_KVHALF;
  char* pbase = (char*)Plds[wave];

  auto stage = [&](int buf, int step) {
    const char* ktile = kbase + (size_t)step * FB_KVSTEP * H_ * 2;
#pragma unroll
    for (int i = 0; i < 4; ++i) {
      int chunk = wave * 4 + i;
      int off = chunk * 1024 + lane * 16;
      int row = off >> 8, col = off & 255;
      gl_lds16(ktile + row * 256 + (col ^ ((row & 7) << 4)),
               (char*)Kbuf[buf] + chunk * 1024);
    }
#pragma unroll
    for (int i = 0; i < 4; ++i) {
      int chunk = wave * 4 + i;
      int h = chunk * 4 + (lane >> 4);
      int colb = (lane & 15) * 16;
      gl_lds16(vbase + (size_t)h * (N_ * 2) + (size_t)step * 256 + (colb ^ ((h & 7) << 4)),
               (char*)Vbuf[buf] + chunk * 1024);
    }
  };

  int cur = 0;
  stage(0, 0);
  __syncthreads();

  for (int step = 0; step < FB_NSTEPS; ++step) {
    if (step + 1 < FB_NSTEPS) stage(cur ^ 1, step + 1);

    const char* Kl = (const char*)Kbuf[cur];
    const char* Vl = (const char*)Vbuf[cur];

    f32x4 S[4];
#pragma unroll
    for (int ct = 0; ct < 4; ++ct) S[ct] = (f32x4){0.f, 0.f, 0.f, 0.f};
#pragma unroll
    for (int ct = 0; ct < 4; ++ct) {
      int kvrow = kvbase + ct * 16 + l15;
#pragma unroll
      for (int kc = 0; kc < 4; ++kc) {
        short8 bfrag = *(const short8*)(Kl +
            ((kvrow * 256 + (8 * l4 + 32 * kc) * 2) ^ ((kvrow & 7) << 4)));
        S[ct] = __builtin_amdgcn_mfma_f32_16x16x32_bf16(qfrag[kc], bfrag, S[ct], 0, 0, 0);
      }
    }

    float mnew[4];
#pragma unroll
    for (int r = 0; r < 4; ++r) {
      float mx = fmaxf(fmaxf(S[0][r], S[1][r]), fmaxf(S[2][r], S[3][r]));
      mx = fmaxf(mx, __shfl_xor(mx, 1));
      mx = fmaxf(mx, __shfl_xor(mx, 2));
      mx = fmaxf(mx, __shfl_xor(mx, 4));
      mx = fmaxf(mx, __shfl_xor(mx, 8));
      mnew[r] = mx;
    }
    float alpha[4];
#pragma unroll
    for (int r = 0; r < 4; ++r) {
      float mi = fmaxf(mrun[r], mnew[r]);
      alpha[r] = __builtin_amdgcn_exp2f(mrun[r] - mi);
      mrun[r] = mi;
    }
    float rsum[4] = {0.f, 0.f, 0.f, 0.f};
    unsigned short pb[4][4];
#pragma unroll
    for (int ct = 0; ct < 4; ++ct)
#pragma unroll
      for (int r = 0; r < 4; ++r) {
        float pv = __builtin_amdgcn_exp2f(S[ct][r] - mrun[r]);
        rsum[r] += pv;
        pb[ct][r] = f2bf(pv);
      }
#pragma unroll
    for (int r = 0; r < 4; ++r) {
      float s = rsum[r];
      s += __shfl_xor(s, 1); s += __shfl_xor(s, 2);
      s += __shfl_xor(s, 4); s += __shfl_xor(s, 8);
      lrun[r] = lrun[r] * alpha[r] + s;
    }
#pragma unroll
    for (int ct2 = 0; ct2 < 8; ++ct2)
#pragma unroll
      for (int r = 0; r < 4; ++r) Oacc[ct2][r] *= alpha[r];

#pragma unroll
    for (int ct = 0; ct < 4; ++ct)
#pragma unroll
      for (int r = 0; r < 4; ++r) {
        int qrow = 4 * l4 + r;
        int kv = l15 + 16 * ct;
        *(unsigned short*)(pbase + ((qrow * 128 + kv * 2) ^ ((qrow & 7) << 4))) = pb[ct][r];
      }

#pragma unroll
    for (int kc2 = 0; kc2 < 2; ++kc2) {
      short8 afrag = *(const short8*)(pbase +
          ((l15 * 128 + (8 * l4 + 32 * kc2) * 2) ^ ((l15 & 7) << 4)));
#pragma unroll
      for (int ct2 = 0; ct2 < 8; ++ct2) {
        int h = l15 + 16 * ct2;
        short8 bfrag = *(const short8*)(Vl +
            ((h * 256 + (kvbase + 8 * l4 + 32 * kc2) * 2) ^ ((h & 7) << 4)));
        Oacc[ct2] = __builtin_amdgcn_mfma_f32_16x16x32_bf16(afrag, bfrag, Oacc[ct2], 0, 0, 0);
      }
    }

    __syncthreads();
    cur ^= 1;
  }

  __syncthreads();
  float* mergeO = (float*)Kbuf;
  if (grp == 1) {
#pragma unroll
    for (int ct2 = 0; ct2 < 8; ++ct2)
#pragma unroll
      for (int r = 0; r < 4; ++r) {
        int qrow = 4 * l4 + r, h = l15 + 16 * ct2;
        mergeO[(sub * 16 + qrow) * H_ + h] = Oacc[ct2][r];
      }
    if (l15 == 0) {
#pragma unroll
      for (int r = 0; r < 4; ++r) {
        int qrow = 4 * l4 + r;
        MLlds[sub][qrow][0] = mrun[r];
        MLlds[sub][qrow][1] = lrun[r];
      }
    }
  }
  __syncthreads();
  if (grp == 0) {
    float aA[4], aB[4], rl[4];
#pragma unroll
    for (int r = 0; r < 4; ++r) {
      int qrow = 4 * l4 + r;
      float mB = MLlds[sub][qrow][0], lB = MLlds[sub][qrow][1];
      float mi = fmaxf(mrun[r], mB);
      aA[r] = __builtin_amdgcn_exp2f(mrun[r] - mi);
      aB[r] = __builtin_amdgcn_exp2f(mB - mi);
      rl[r] = 1.f / (lrun[r] * aA[r] + lB * aB[r]);
    }
    float* outp = out + ((size_t)b * N_ + qbase + sub * 16) * H_;
#pragma unroll
    for (int ct2 = 0; ct2 < 8; ++ct2)
#pragma unroll
      for (int r = 0; r < 4; ++r) {
        int qrow = 4 * l4 + r, h = l15 + 16 * ct2;
        float ob = mergeO[(sub * 16 + qrow) * H_ + h];
        outp[(size_t)qrow * H_ + h] = (Oacc[ct2][r] * aA[r] + ob * aB[r]) * rl[r];
      }
  }
}

extern "C" void kernel_launch(void* const* d_in, const int* in_sizes, int n_in,
                              void* d_out, int out_size, void* d_ws, size_t ws_size,
                              hipStream_t stream) {
  const float* q = (const float*)d_in[0];
  const float* k = (const float*)d_in[1];
  const float* v = (const float*)d_in[2];
  float* out = (float*)d_out;

  // qb/kb/vt (3*TSB) + bf16 opart (KS*ELEMS*2) + f32 mlpart (KS*B*N*2*4)
  const size_t need19 = 3 * TSB + (size_t)KS8 * ELEMS * 2 + (size_t)KS8 * B_ * N_ * 2 * 4;

  if (ws_size >= need19) {
    unsigned short* qb = (unsigned short*)d_ws;
    unsigned short* kb = qb + ELEMS;
    unsigned short* vt = kb + ELEMS;
    unsigned short* opart = (unsigned short*)((char*)d_ws + 3 * TSB);
    float* mlpart = (float*)(opart + (size_t)KS8 * ELEMS);
    conv_all<<<dim3(1536), dim3(256), 0, stream>>>(q, k, v, qb, kb, vt);
    fattn_v19<<<dim3(32 * B_ * KS8), dim3(NTH), 0, stream>>>(qb, kb, vt, opart, mlpart);
    combine_k<KS8><<<dim3(B_ * N_ / 8), dim3(256), 0, stream>>>(opart, mlpart, out);
  } else if (ws_size >= 3 * TSB) {
    unsigned short* qb = (unsigned short*)d_ws;
    unsigned short* kb = qb + ELEMS;
    unsigned short* vt = kb + ELEMS;
    conv_all<<<dim3(1536), dim3(256), 0, stream>>>(q, k, v, qb, kb, vt);
    fattn_fast<<<dim3(N_ / FB_QTILE, B_), dim3(FB_NTH), 0, stream>>>(qb, kb, vt, out);
  }
}

// Round 20
// 60.622 us; speedup vs baseline: 1.1306x; 1.1306x over previous
//
#include <hip/hip_runtime.h>

typedef __attribute__((ext_vector_type(4)))  float f32x4;
typedef __attribute__((ext_vector_type(16))) float f32x16;
typedef __attribute__((ext_vector_type(8)))  short short8;

#define DEVI static __device__ __forceinline__

constexpr int B_ = 4;
constexpr int N_ = 4096;
constexpr int H_ = 128;
constexpr size_t ELEMS = (size_t)B_ * N_ * H_;   // per tensor
constexpr size_t TSB = ELEMS * 2;                // bf16 bytes per tensor

// ---- v20 = R18 (best measured: 60.7 us total): KVB=32, 4 waves, 2 blocks/CU, KS=4 ----
constexpr int QT = 128;
constexpr int KVB = 32;
constexpr int NTH = 256;
constexpr int KS4 = 4;

DEVI unsigned short f2bf(float x) {
  union { float f; unsigned u; } a; a.f = x;
  unsigned u = a.u;
  return (unsigned short)((u + 0x7FFFu + ((u >> 16) & 1u)) >> 16);  // RNE
}

DEVI unsigned cvt_pk_bf16(float lo, float hi) {
  unsigned w;
  asm("v_cvt_pk_bf16_f32 %0, %1, %2" : "=v"(w) : "v"(lo), "v"(hi));
  return w;
}

DEVI float bf2f(unsigned short u) {
  union { unsigned u; float f; } a; a.u = (unsigned)u << 16;
  return a.f;
}

DEVI void gl_lds16(const void* g, void* l) {
  __builtin_amdgcn_global_load_lds(
      (const __attribute__((address_space(1))) void*)g,
      (__attribute__((address_space(3))) void*)l, 16, 0, 0);
}

// ---------------- merged pre-pass: Q(scaled)/K bf16 + V^T bf16 ----------------
__global__ void conv_all(const float* __restrict__ q, const float* __restrict__ k,
                         const float* __restrict__ v,
                         unsigned short* __restrict__ qb, unsigned short* __restrict__ kb,
                         unsigned short* __restrict__ vt) {
  __shared__ unsigned short T[64][72];
  const int bid = blockIdx.x;
  const int t = threadIdx.x;
  if (bid < 1024) {
    const float qscale = 0.08838834764831845f * 1.4426950408889634f;  // 1/sqrt(H)*log2e
    size_t i = (size_t)bid * 256 + t;  // vec8 index
    {
      const float4* s = (const float4*)q + 2 * i;
      float4 a = s[0], b = s[1];
      short8 o;
      o[0] = (short)f2bf(a.x * qscale); o[1] = (short)f2bf(a.y * qscale);
      o[2] = (short)f2bf(a.z * qscale); o[3] = (short)f2bf(a.w * qscale);
      o[4] = (short)f2bf(b.x * qscale); o[5] = (short)f2bf(b.y * qscale);
      o[6] = (short)f2bf(b.z * qscale); o[7] = (short)f2bf(b.w * qscale);
      *(short8*)(qb + i * 8) = o;
    }
    {
      const float4* s = (const float4*)k + 2 * i;
      float4 a = s[0], b = s[1];
      short8 o;
      o[0] = (short)f2bf(a.x); o[1] = (short)f2bf(a.y);
      o[2] = (short)f2bf(a.z); o[3] = (short)f2bf(a.w);
      o[4] = (short)f2bf(b.x); o[5] = (short)f2bf(b.y);
      o[6] = (short)f2bf(b.z); o[7] = (short)f2bf(b.w);
      *(short8*)(kb + i * 8) = o;
    }
  } else {
    const int vb = bid - 1024;          // 512 tiles: [64 n][64 h]
    const int n0 = (vb & 63) * 64, h0 = ((vb >> 6) & 1) * 64, b = vb >> 7;
    const int c4 = t & 15, r = t >> 4;
#pragma unroll
    for (int i = 0; i < 4; ++i) {
      int n = n0 + r + 16 * i;
      float4 val = *(const float4*)(v + ((size_t)b * N_ + n) * H_ + h0 + 4 * c4);
      T[4 * c4 + 0][r + 16 * i] = f2bf(val.x);
      T[4 * c4 + 1][r + 16 * i] = f2bf(val.y);
      T[4 * c4 + 2][r + 16 * i] = f2bf(val.z);
      T[4 * c4 + 3][r + 16 * i] = f2bf(val.w);
    }
    __syncthreads();
    const int c8 = t & 7, hr = t >> 3;
#pragma unroll
    for (int i = 0; i < 2; ++i) {
      int hl = hr + 32 * i;
      short8 val = *(const short8*)(&T[hl][8 * c8]);
      *(short8*)(vt + ((size_t)b * H_ + h0 + hl) * N_ + n0 + 8 * c8) = val;
    }
  }
}

// ------- main v20 (= R18): rotated pipeline + speculative P-pack + lane-local l -------
__global__ __launch_bounds__(NTH, 2)
void fattn_v20(const unsigned short* __restrict__ qws,
               const unsigned short* __restrict__ kws,
               const unsigned short* __restrict__ vtws,
               unsigned short* __restrict__ opart, float* __restrict__ mlpart) {
  constexpr int KS = KS4;
  constexpr int KVRANGE = N_ / KS;     // 1024
  constexpr int NST = KVRANGE / KVB;   // 32

  __shared__ __align__(16) char smem[36864];
  char* Kb0 = smem;              // 2 x 8192: K [32 kv][256B], swz (row&15)<<4
  char* Vb0 = smem + 16384;      // 2 x 10240: V^T padded [128 h][80B]

  const int tid = threadIdx.x, wave = tid >> 6, lane = tid & 63;
  const int l31 = lane & 31, half = lane >> 5;

  // 512 blocks: xcd = bid&7 owns 2 (b,z) pairs -> K/V slices L2-resident
  const int bid = blockIdx.x;
  const int pair = (bid & 7) * 2 + ((bid >> 3) & 1);
  const int x = bid >> 4;              // q-tile 0..31
  const int b = pair / KS, z = pair % KS;

  const int qg0 = x * QT + wave * 32;
  const size_t kvz = (size_t)z * KVRANGE;

  const unsigned short* qp0 = qws + ((size_t)b * N_ + qg0 + l31) * H_ + 8 * half;
  short8 qf[8];
#pragma unroll
  for (int c = 0; c < 8; ++c) qf[c] = *(const short8*)(qp0 + 16 * c);

  f32x16 O0 = {}, O1 = {}, O2 = {}, O3 = {};
  float m = 0.f, l = 0.f;        // m wave-uniform; l LANE-LOCAL (half-row sum)

  const char* kbase = (const char*)(kws + ((size_t)b * N_ + kvz) * H_);
  const char* vbase = (const char*)(vtws + (size_t)b * H_ * N_) + kvz * 2;

  const int vh = tid >> 1;             // V staging: h row (2 thr/row)
  const int vc = (tid & 1) * 2;        // chunk base {0,2} x16B

  // ---- prologue: stage K(0) ----
#pragma unroll
  for (int i = 0; i < 2; ++i) {
    int off = (tid + 256 * i) * 16;
    int row = off >> 8, col = off & 255;
    gl_lds16(kbase + row * 256 + (col ^ ((row & 15) << 4)), Kb0 + off);
  }
  __syncthreads();

  const int kswz = (l31 & 15) << 4;
  const int kcol = 16 * half;
  short8 pfa = {}, pfb = {};           // P frags carried across iterations

  for (int st = 0; st < NST; ++st) {
    // ---- issue staging: K(st+1) via gl_lds, V(st) into regs ----
    if (st + 1 < NST) {
      const char* kt = kbase + (size_t)(st + 1) * KVB * H_ * 2;
      char* kd = Kb0 + ((st + 1) & 1) * 8192;
#pragma unroll
      for (int i = 0; i < 2; ++i) {
        int off = (tid + 256 * i) * 16;
        int row = off >> 8, col = off & 255;
        gl_lds16(kt + row * 256 + (col ^ ((row & 15) << 4)), kd + off);
      }
    }
    const char* vsrc = vbase + (size_t)st * KVB * 2 + (size_t)vh * (N_ * 2) + vc * 16;
    uint4 vr0 = *(const uint4*)(vsrc);
    uint4 vr1 = *(const uint4*)(vsrc + 16);

    // ---- MFMA cluster: PV(st-1) + QKT(st) ----
    __builtin_amdgcn_s_setprio(1);
    if (st > 0) {
      const char* Vl = Vb0 + ((st - 1) & 1) * 10240;
      const char* vrow = Vl + l31 * 80 + 16 * half;
      short8 a00 = *(const short8*)(vrow + 0 * 2560);
      short8 a10 = *(const short8*)(vrow + 1 * 2560);
      short8 a20 = *(const short8*)(vrow + 2 * 2560);
      short8 a30 = *(const short8*)(vrow + 3 * 2560);
      O0 = __builtin_amdgcn_mfma_f32_32x32x16_bf16(a00, pfa, O0, 0, 0, 0);
      O1 = __builtin_amdgcn_mfma_f32_32x32x16_bf16(a10, pfa, O1, 0, 0, 0);
      O2 = __builtin_amdgcn_mfma_f32_32x32x16_bf16(a20, pfa, O2, 0, 0, 0);
      O3 = __builtin_amdgcn_mfma_f32_32x32x16_bf16(a30, pfa, O3, 0, 0, 0);
      short8 a01 = *(const short8*)(vrow + 32 + 0 * 2560);
      short8 a11 = *(const short8*)(vrow + 32 + 1 * 2560);
      short8 a21 = *(const short8*)(vrow + 32 + 2 * 2560);
      short8 a31 = *(const short8*)(vrow + 32 + 3 * 2560);
      O0 = __builtin_amdgcn_mfma_f32_32x32x16_bf16(a01, pfb, O0, 0, 0, 0);
      O1 = __builtin_amdgcn_mfma_f32_32x32x16_bf16(a11, pfb, O1, 0, 0, 0);
      O2 = __builtin_amdgcn_mfma_f32_32x32x16_bf16(a21, pfb, O2, 0, 0, 0);
      O3 = __builtin_amdgcn_mfma_f32_32x32x16_bf16(a31, pfb, O3, 0, 0, 0);
    }
    {
      const char* Kl = Kb0 + (st & 1) * 8192;
      f32x16 S = {};
#pragma unroll
      for (int c = 0; c < 8; ++c) {
        short8 af = *(const short8*)(Kl + l31 * 256 + ((32 * c + kcol) ^ kswz));
        S = __builtin_amdgcn_mfma_f32_32x32x16_bf16(af, qf[c], S, 0, 0, 0);
      }
      __builtin_amdgcn_s_setprio(0);

      // ---- SM(st): p = exp2(S - m); speculative pack, lane-local rs/l ----
      float p[16];
#pragma unroll
      for (int i = 0; i < 16; ++i) p[i] = __builtin_amdgcn_exp2f(S[i] - m);
      unsigned u0 = cvt_pk_bf16(p[0], p[1]),   u1 = cvt_pk_bf16(p[2], p[3]);
      unsigned u2 = cvt_pk_bf16(p[4], p[5]),   u3 = cvt_pk_bf16(p[6], p[7]);
      unsigned u4 = cvt_pk_bf16(p[8], p[9]),   u5 = cvt_pk_bf16(p[10], p[11]);
      unsigned u6 = cvt_pk_bf16(p[12], p[13]), u7 = cvt_pk_bf16(p[14], p[15]);
      unsigned ra = __shfl_xor((int)(half ? u0 : u2), 32);
      unsigned rb = __shfl_xor((int)(half ? u1 : u3), 32);
      unsigned rc = __shfl_xor((int)(half ? u4 : u6), 32);
      unsigned rd = __shfl_xor((int)(half ? u5 : u7), 32);
      union { unsigned u[4]; short8 s; } f0, f1;
      f0.u[0] = half ? ra : u0;  f0.u[1] = half ? rb : u1;
      f0.u[2] = half ? u2 : ra;  f0.u[3] = half ? u3 : rb;
      f1.u[0] = half ? rc : u4;  f1.u[1] = half ? rd : u5;
      f1.u[2] = half ? u6 : rc;  f1.u[3] = half ? u7 : rd;
      pfa = f0.s;
      pfb = f1.s;

      float rs = (((p[0] + p[1]) + (p[2] + p[3])) + ((p[4] + p[5]) + (p[6] + p[7]))) +
                 (((p[8] + p[9]) + (p[10] + p[11])) + ((p[12] + p[13]) + (p[14] + p[15])));
      l += rs;   // lane-local half-row sum; reduced once in epilogue
      if (__builtin_expect(!__all(rs <= 524288.f), 0)) {
        // cold path: full rescale + repack
        float rsw = rs + __shfl_xor(rs, 32);
        float ai = 1.f / rsw;
        m += __builtin_amdgcn_logf(rsw);       // v_log_f32 = log2
        l *= ai;
#pragma unroll
        for (int i = 0; i < 16; ++i) p[i] *= ai;
#pragma unroll
        for (int i = 0; i < 16; ++i) { O0[i] *= ai; O1[i] *= ai; O2[i] *= ai; O3[i] *= ai; }
        unsigned v0 = cvt_pk_bf16(p[0], p[1]),   v1 = cvt_pk_bf16(p[2], p[3]);
        unsigned v2 = cvt_pk_bf16(p[4], p[5]),   v3 = cvt_pk_bf16(p[6], p[7]);
        unsigned v4 = cvt_pk_bf16(p[8], p[9]),   v5 = cvt_pk_bf16(p[10], p[11]);
        unsigned v6 = cvt_pk_bf16(p[12], p[13]), v7 = cvt_pk_bf16(p[14], p[15]);
        unsigned sa = __shfl_xor((int)(half ? v0 : v2), 32);
        unsigned sb = __shfl_xor((int)(half ? v1 : v3), 32);
        unsigned sc2 = __shfl_xor((int)(half ? v4 : v6), 32);
        unsigned sd = __shfl_xor((int)(half ? v5 : v7), 32);
        union { unsigned u[4]; short8 s; } g0, g1;
        g0.u[0] = half ? sa : v0;  g0.u[1] = half ? sb : v1;
        g0.u[2] = half ? v2 : sa;  g0.u[3] = half ? v3 : sb;
        g1.u[0] = half ? sc2 : v4; g1.u[1] = half ? sd : v5;
        g1.u[2] = half ? v6 : sc2; g1.u[3] = half ? v7 : sd;
        pfa = g0.s;
        pfb = g1.s;
      }
    }

    // ---- late write of V(st) regs (vmcnt wait covers K(st+1) gl_lds too) ----
    {
      char* vd = Vb0 + (st & 1) * 10240 + vh * 80 + vc * 16;
      *(uint4*)(vd) = vr0;
      *(uint4*)(vd + 16) = vr1;
    }
    __syncthreads();
  }

  // ---- epilogue: final PV(NST-1) ----
  {
    const char* Vl = Vb0 + ((NST - 1) & 1) * 10240;
    const char* vrow = Vl + l31 * 80 + 16 * half;
#pragma unroll
    for (int t2 = 0; t2 < 4; ++t2) {
      short8 a0 = *(const short8*)(vrow + t2 * 2560);
      short8 a1 = *(const short8*)(vrow + 32 + t2 * 2560);
      f32x16 acc = (t2 == 0) ? O0 : (t2 == 1) ? O1 : (t2 == 2) ? O2 : O3;
      acc = __builtin_amdgcn_mfma_f32_32x32x16_bf16(a0, pfa, acc, 0, 0, 0);
      acc = __builtin_amdgcn_mfma_f32_32x32x16_bf16(a1, pfb, acc, 0, 0, 0);
      if (t2 == 0) O0 = acc; else if (t2 == 1) O1 = acc; else if (t2 == 2) O2 = acc; else O3 = acc;
    }
  }

  // ---- l: reduce lane-local halves once ----
  float lw = l + __shfl_xor(l, 32);

  // ---- stores (bf16 partials): lane q = l31, h = 32*t2 + 8g + 4*half + j ----
  const size_t zb = (size_t)z * B_ + b;
  if (half == 0) {
    float2 ml = {m, lw};
    *(float2*)(mlpart + 2 * (zb * N_ + qg0 + l31)) = ml;
  }
  unsigned short* od = opart + (zb * N_ + qg0 + l31) * H_ + 4 * half;
#pragma unroll
  for (int g = 0; g < 4; ++g) {
    uint2 w0 = {cvt_pk_bf16(O0[4 * g], O0[4 * g + 1]), cvt_pk_bf16(O0[4 * g + 2], O0[4 * g + 3])};
    uint2 w1 = {cvt_pk_bf16(O1[4 * g], O1[4 * g + 1]), cvt_pk_bf16(O1[4 * g + 2], O1[4 * g + 3])};
    uint2 w2 = {cvt_pk_bf16(O2[4 * g], O2[4 * g + 1]), cvt_pk_bf16(O2[4 * g + 2], O2[4 * g + 3])};
    uint2 w3 = {cvt_pk_bf16(O3[4 * g], O3[4 * g + 1]), cvt_pk_bf16(O3[4 * g + 2], O3[4 * g + 3])};
    *(uint2*)(od + 8 * g) = w0;
    *(uint2*)(od + 32 + 8 * g) = w1;
    *(uint2*)(od + 64 + 8 * g) = w2;
    *(uint2*)(od + 96 + 8 * g) = w3;
  }
}

// ---------------- combine the KS kv-split partials (bf16 opart) ----------------
template <int KS>
__global__ void combine_k(const unsigned short* __restrict__ opart,
                          const float* __restrict__ mlpart,
                          float* __restrict__ out) {
  const int t = threadIdx.x;
  size_t row = (size_t)blockIdx.x * 8 + (t >> 5);
  int hc = (t & 31) * 4;
  float mz[KS], lz[KS];
  float mi = -__builtin_inff();
#pragma unroll
  for (int z = 0; z < KS; ++z) {
    size_t r = (size_t)z * B_ * N_ + row;
    mz[z] = mlpart[2 * r];
    lz[z] = mlpart[2 * r + 1];
    mi = fmaxf(mi, mz[z]);
  }
  float lsum = 0.f;
  float az[KS];
#pragma unroll
  for (int z = 0; z < KS; ++z) {
    az[z] = __builtin_amdgcn_exp2f(mz[z] - mi);
    lsum += az[z] * lz[z];
  }
  float rinv = 1.f / lsum;
  f32x4 acc = {};
#pragma unroll
  for (int z = 0; z < KS; ++z) {
    const unsigned short* op = opart + (size_t)z * B_ * N_ * H_ + row * H_ + hc;
    ushort4 u = *(const ushort4*)(op);
    f32x4 oz = {bf2f(u.x), bf2f(u.y), bf2f(u.z), bf2f(u.w)};
    acc = acc + oz * (az[z] * rinv);
  }
  *(f32x4*)(out + row * H_ + hc) = acc;
}

// ================= fallback path (minimal ws): R2-proven pipeline =================
constexpr int FB_QTILE = 64;
constexpr int FB_KVSTEP = 128;
constexpr int FB_KVHALF = 64;
constexpr int FB_NTH = 512;
constexpr int FB_NSTEPS = N_ / FB_KVSTEP;

__global__ __launch_bounds__(FB_NTH, 2)
void fattn_fast(const unsigned short* __restrict__ qws,
                const unsigned short* __restrict__ kws,
                const unsigned short* __restrict__ vtws,
                float* __restrict__ out) {
  __shared__ unsigned short Kbuf[2][FB_KVSTEP * H_];
  __shared__ unsigned short Vbuf[2][H_ * FB_KVSTEP];
  __shared__ unsigned short Plds[8][16 * FB_KVHALF];
  __shared__ float MLlds[4][16][2];

  const int tid = threadIdx.x;
  const int wave = tid >> 6;
  const int lane = tid & 63;
  const int l15 = lane & 15;
  const int l4 = lane >> 4;
  const int sub = wave & 3;
  const int grp = wave >> 2;

  const int b = blockIdx.y;
  const int qbase = blockIdx.x * FB_QTILE;

  const unsigned short* qp = qws + ((size_t)b * N_ + qbase + sub * 16 + l15) * H_;
  short8 qfrag[4];
#pragma unroll
  for (int kc = 0; kc < 4; ++kc)
    qfrag[kc] = *(const short8*)(qp + 8 * l4 + 32 * kc);

  f32x4 Oacc[8];
#pragma unroll
  for (int i = 0; i < 8; ++i) Oacc[i] = (f32x4){0.f, 0.f, 0.f, 0.f};
  float mrun[4], lrun[4];
#pragma unroll
  for (int r = 0; r < 4; ++r) { mrun[r] = -__builtin_inff(); lrun[r] = 0.f; }

  const char* kbase = (const char*)(kws + (size_t)b * N_ * H_);
  const char* vbase = (const char*)(vtws + (size_t)b * H_ * N_);
  const int kvbase = grp * FB_KVHALF;
  char* pbase = (char*)Plds[wave];

  auto stage = [&](int buf, int step) {
    const char* ktile = kbase + (size_t)step * FB_KVSTEP * H_ * 2;
#pragma unroll
    for (int i = 0; i < 4; ++i) {
      int chunk = wave * 4 + i;
      int off = chunk * 1024 + lane * 16;
      int row = off >> 8, col = off & 255;
      gl_lds16(ktile + row * 256 + (col ^ ((row & 7) << 4)),
               (char*)Kbuf[buf] + chunk * 1024);
    }
#pragma unroll
    for (int i = 0; i < 4; ++i) {
      int chunk = wave * 4 + i;
      int h = chunk * 4 + (lane >> 4);
      int colb = (lane & 15) * 16;
      gl_lds16(vbase + (size_t)h * (N_ * 2) + (size_t)step * 256 + (colb ^ ((h & 7) << 4)),
               (char*)Vbuf[buf] + chunk * 1024);
    }
  };

  int cur = 0;
  stage(0, 0);
  __syncthreads();

  for (int step = 0; step < FB_NSTEPS; ++step) {
    if (step + 1 < FB_NSTEPS) stage(cur ^ 1, step + 1);

    const char* Kl = (const char*)Kbuf[cur];
    const char* Vl = (const char*)Vbuf[cur];

    f32x4 S[4];
#pragma unroll
    for (int ct = 0; ct < 4; ++ct) S[ct] = (f32x4){0.f, 0.f, 0.f, 0.f};
#pragma unroll
    for (int ct = 0; ct < 4; ++ct) {
      int kvrow = kvbase + ct * 16 + l15;
#pragma unroll
      for (int kc = 0; kc < 4; ++kc) {
        short8 bfrag = *(const short8*)(Kl +
            ((kvrow * 256 + (8 * l4 + 32 * kc) * 2) ^ ((kvrow & 7) << 4)));
        S[ct] = __builtin_amdgcn_mfma_f32_16x16x32_bf16(qfrag[kc], bfrag, S[ct], 0, 0, 0);
      }
    }

    float mnew[4];
#pragma unroll
    for (int r = 0; r < 4; ++r) {
      float mx = fmaxf(fmaxf(S[0][r], S[1][r]), fmaxf(S[2][r], S[3][r]));
      mx = fmaxf(mx, __shfl_xor(mx, 1));
      mx = fmaxf(mx, __shfl_xor(mx, 2));
      mx = fmaxf(mx, __shfl_xor(mx, 4));
      mx = fmaxf(mx, __shfl_xor(mx, 8));
      mnew[r] = mx;
    }
    float alpha[4];
#pragma unroll
    for (int r = 0; r < 4; ++r) {
      float mi = fmaxf(mrun[r], mnew[r]);
      alpha[r] = __builtin_amdgcn_exp2f(mrun[r] - mi);
      mrun[r] = mi;
    }
    float rsum[4] = {0.f, 0.f, 0.f, 0.f};
    unsigned short pb[4][4];
#pragma unroll
    for (int ct = 0; ct < 4; ++ct)
#pragma unroll
      for (int r = 0; r < 4; ++r) {
        float pv = __builtin_amdgcn_exp2f(S[ct][r] - mrun[r]);
        rsum[r] += pv;
        pb[ct][r] = f2bf(pv);
      }
#pragma unroll
    for (int r = 0; r < 4; ++r) {
      float s = rsum[r];
      s += __shfl_xor(s, 1); s += __shfl_xor(s, 2);
      s += __shfl_xor(s, 4); s += __shfl_xor(s, 8);
      lrun[r] = lrun[r] * alpha[r] + s;
    }
#pragma unroll
    for (int ct2 = 0; ct2 < 8; ++ct2)
#pragma unroll
      for (int r = 0; r < 4; ++r) Oacc[ct2][r] *= alpha[r];

#pragma unroll
    for (int ct = 0; ct < 4; ++ct)
#pragma unroll
      for (int r = 0; r < 4; ++r) {
        int qrow = 4 * l4 + r;
        int kv = l15 + 16 * ct;
        *(unsigned short*)(pbase + ((qrow * 128 + kv * 2) ^ ((qrow & 7) << 4))) = pb[ct][r];
      }

#pragma unroll
    for (int kc2 = 0; kc2 < 2; ++kc2) {
      short8 afrag = *(const short8*)(pbase +
          ((l15 * 128 + (8 * l4 + 32 * kc2) * 2) ^ ((l15 & 7) << 4)));
#pragma unroll
      for (int ct2 = 0; ct2 < 8; ++ct2) {
        int h = l15 + 16 * ct2;
        short8 bfrag = *(const short8*)(Vl +
            ((h * 256 + (kvbase + 8 * l4 + 32 * kc2) * 2) ^ ((h & 7) << 4)));
        Oacc[ct2] = __builtin_amdgcn_mfma_f32_16x16x32_bf16(afrag, bfrag, Oacc[ct2], 0, 0, 0);
      }
    }

    __syncthreads();
    cur ^= 1;
  }

  __syncthreads();
  float* mergeO = (float*)Kbuf;
  if (grp == 1) {
#pragma unroll
    for (int ct2 = 0; ct2 < 8; ++ct2)
#pragma unroll
      for (int r = 0; r < 4; ++r) {
        int qrow = 4 * l4 + r, h = l15 + 16 * ct2;
        mergeO[(sub * 16 + qrow) * H_ + h] = Oacc[ct2][r];
      }
    if (l15 == 0) {
#pragma unroll
      for (int r = 0; r < 4; ++r) {
        int qrow = 4 * l4 + r;
        MLlds[sub][qrow][0] = mrun[r];
        MLlds[sub][qrow][1] = lrun[r];
      }
    }
  }
  __syncthreads();
  if (grp == 0) {
    float aA[4], aB[4], rl[4];
#pragma unroll
    for (int r = 0; r < 4; ++r) {
      int qrow = 4 * l4 + r;
      float mB = MLlds[sub][qrow][0], lB = MLlds[sub][qrow][1];
      float mi = fmaxf(mrun[r], mB);
      aA[r] = __builtin_amdgcn_exp2f(mrun[r] - mi);
      aB[r] = __builtin_amdgcn_exp2f(mB - mi);
      rl[r] = 1.f / (lrun[r] * aA[r] + lB * aB[r]);
    }
    float* outp = out + ((size_t)b * N_ + qbase + sub * 16) * H_;
#pragma unroll
    for (int ct2 = 0; ct2 < 8; ++ct2)
#pragma unroll
      for (int r = 0; r < 4; ++r) {
        int qrow = 4 * l4 + r, h = l15 + 16 * ct2;
        float ob = mergeO[(sub * 16 + qrow) * H_ + h];
        outp[(size_t)qrow * H_ + h] = (Oacc[ct2][r] * aA[r] + ob * aB[r]) * rl[r];
      }
  }
}

extern "C" void kernel_launch(void* const* d_in, const int* in_sizes, int n_in,
                              void* d_out, int out_size, void* d_ws, size_t ws_size,
                              hipStream_t stream) {
  const float* q = (const float*)d_in[0];
  const float* k = (const float*)d_in[1];
  const float* v = (const float*)d_in[2];
  float* out = (float*)d_out;

  // qb/kb/vt (3*TSB) + bf16 opart (KS*ELEMS*2) + f32 mlpart (KS*B*N*2*4)
  const size_t need20 = 3 * TSB + (size_t)KS4 * ELEMS * 2 + (size_t)KS4 * B_ * N_ * 2 * 4;

  if (ws_size >= need20) {
    unsigned short* qb = (unsigned short*)d_ws;
    unsigned short* kb = qb + ELEMS;
    unsigned short* vt = kb + ELEMS;
    unsigned short* opart = (unsigned short*)((char*)d_ws + 3 * TSB);
    float* mlpart = (float*)(opart + (size_t)KS4 * ELEMS);
    conv_all<<<dim3(1536), dim3(256), 0, stream>>>(q, k, v, qb, kb, vt);
    fattn_v20<<<dim3(32 * B_ * KS4), dim3(NTH), 0, stream>>>(qb, kb, vt, opart, mlpart);
    combine_k<KS4><<<dim3(B_ * N_ / 8), dim3(256), 0, stream>>>(opart, mlpart, out);
  } else if (ws_size >= 3 * TSB) {
    unsigned short* qb = (unsigned short*)d_ws;
    unsigned short* kb = qb + ELEMS;
    unsigned short* vt = kb + ELEMS;
    conv_all<<<dim3(1536), dim3(256), 0, stream>>>(q, k, v, qb, kb, vt);
    fattn_fast<<<dim3(N_ / FB_QTILE, B_), dim3(FB_NTH), 0, stream>>>(qb, kb, vt, out);
  }
}